// Round 7
// baseline (78.748 us; speedup 1.0000x reference)
//
#include <hip/hip_runtime.h>
#include <hip/hip_fp16.h>

#define IN_DIM  16384
#define OUT_DIM 16384
#define BATCH   2048
#define NBLK    256
#define RPB     (BATCH / NBLK)   // 8 rows per block
#define NPAIR   (RPB / 2)        // 4 pair-steps
#define TPB     512
#define ITS     (OUT_DIM / (TPB * 4))   // 8 j-iterations (4 columns each)
#define CHK     (IN_DIM / (TPB * 2))    // 16 float2-chunks per thread per row

typedef float f32x4 __attribute__((ext_vector_type(4)));

// Two half2's per output column: ab = (c0, c1), cd = (c2, c3). 8 bytes.
struct h2x2 { __half2 ab, cd; };

// OP_COEFFS from the reference, row-major [16][4]
__device__ __constant__ float OPC[16][4] = {
    {0.f, 0.f, 0.f, 0.f}, {0.f, 0.f, 0.f, 1.f}, {0.f, 1.f, 0.f, -1.f}, {0.f, 1.f, 0.f, 0.f},
    {0.f, 0.f, 1.f, -1.f}, {0.f, 0.f, 1.f, 0.f}, {0.f, 1.f, 1.f, -2.f}, {0.f, 1.f, 1.f, -1.f},
    {1.f, -1.f, -1.f, 1.f}, {1.f, -1.f, -1.f, 2.f}, {1.f, 0.f, -1.f, 0.f}, {1.f, 0.f, -1.f, 1.f},
    {1.f, -1.f, 0.f, 0.f}, {1.f, -1.f, 0.f, 1.f}, {1.f, 0.f, 0.f, -1.f}, {1.f, 0.f, 0.f, 0.f}};

// Prep: coef (f16x4) + packed LDS byte offsets (idx*4, 16-bit fields).
__global__ __launch_bounds__(256) void prep_kernel(const float* __restrict__ w,
                                                   const int* __restrict__ ia,
                                                   const int* __restrict__ ib,
                                                   h2x2* __restrict__ coefh,
                                                   unsigned* __restrict__ packed) {
    int j = blockIdx.x * 256 + threadIdx.x;
    if (j >= OUT_DIM) return;

    const float4* wr = (const float4*)(w + (size_t)j * 16);
    float wv[16];
    float4 w0 = wr[0], w1 = wr[1], w2 = wr[2], w3 = wr[3];
    wv[0] = w0.x; wv[1] = w0.y; wv[2] = w0.z; wv[3] = w0.w;
    wv[4] = w1.x; wv[5] = w1.y; wv[6] = w1.z; wv[7] = w1.w;
    wv[8] = w2.x; wv[9] = w2.y; wv[10] = w2.z; wv[11] = w2.w;
    wv[12] = w3.x; wv[13] = w3.y; wv[14] = w3.z; wv[15] = w3.w;

    float m = wv[0];
#pragma unroll
    for (int k = 1; k < 16; ++k) m = fmaxf(m, wv[k]);
    float s = 0.f;
#pragma unroll
    for (int k = 0; k < 16; ++k) { wv[k] = expf(wv[k] - m); s += wv[k]; }
    float inv = 1.f / s;

    float c0 = 0.f, c1 = 0.f, c2 = 0.f, c3 = 0.f;
#pragma unroll
    for (int k = 0; k < 16; ++k) {
        float p = wv[k];
        c0 = fmaf(p, OPC[k][0], c0);
        c1 = fmaf(p, OPC[k][1], c1);
        c2 = fmaf(p, OPC[k][2], c2);
        c3 = fmaf(p, OPC[k][3], c3);
    }
    h2x2 c;
    c.ab = __floats2half2_rn(c0 * inv, c1 * inv);
    c.cd = __floats2half2_rn(c2 * inv, c3 * inv);
    coefh[j] = c;
    packed[j] = ((unsigned)ia[j] << 2) | ((unsigned)ib[j] << 18);
}

// Paired-row interleaved gather. LDS holds TWO rows interleaved as float2
// pairs: lds byte 8p = {rowA[p], rowB[p]}. One ds_read_b64 serves both rows
// -> half the gather instructions, half the barriers, 2x the HBM burst/step.
// coef/packed hoisted in registers (row-invariant); inner loop: zero VMEM loads.
__global__ __launch_bounds__(TPB, 2) void logic_kernel(const float* __restrict__ x,
                                                       const unsigned* __restrict__ packed,
                                                       const h2x2* __restrict__ coefh,
                                                       float* __restrict__ out) {
    __shared__ float2 lds[IN_DIM];  // 128 KiB interleaved pair buffer, 1 block/CU

    const int tid = threadIdx.x;
    const int row0 = blockIdx.x * RPB;

    // Hoist per-thread coef/packed (same output columns for every row).
    uint4 pk[ITS];      // 32 VGPRs
    h2x2 cf[ITS][4];    // 64 VGPRs
#pragma unroll
    for (int it = 0; it < ITS; ++it) {
        const int j0 = (it * TPB + tid) * 4;
        pk[it] = *(const uint4*)(packed + j0);
        cf[it][0] = coefh[j0 + 0];
        cf[it][1] = coefh[j0 + 1];
        cf[it][2] = coefh[j0 + 2];
        cf[it][3] = coefh[j0 + 3];
    }

    float2 ta[CHK], tb[CHK];  // 64 VGPRs staging (row pair in flight)

    // Prologue: load pair 0 and ds_write interleaved.
    {
        const float2* sa = (const float2*)(x + (size_t)(row0 + 0) * IN_DIM);
        const float2* sb = (const float2*)(x + (size_t)(row0 + 1) * IN_DIM);
#pragma unroll
        for (int c = 0; c < CHK; ++c) {
            const int m = c * TPB + tid;
            ta[c] = sa[m];
            tb[c] = sb[m];
        }
#pragma unroll
        for (int c = 0; c < CHK; ++c) {
            const int m = c * TPB + tid;
            // bytes [16m,16m+16) = {A[2m], B[2m], A[2m+1], B[2m+1]}
            *(f32x4*)((char*)lds + (size_t)m * 16) =
                f32x4{ta[c].x, tb[c].x, ta[c].y, tb[c].y};
        }
    }

    for (int s = 0; s < NPAIR; ++s) {
        __syncthreads();  // pair s staged & visible to all waves

        const bool pf = (s + 1 < NPAIR);
        if (pf) {
            const float2* sa = (const float2*)(x + (size_t)(row0 + 2 * s + 2) * IN_DIM);
            const float2* sb = (const float2*)(x + (size_t)(row0 + 2 * s + 3) * IN_DIM);
#pragma unroll
            for (int c = 0; c < CHK; ++c) {
                const int m = c * TPB + tid;
                ta[c] = sa[m];
                tb[c] = sb[m];
            }
        }
        __builtin_amdgcn_sched_barrier(0);  // pin prefetch load issue before compute

        const char* buf = (const char*)lds;
        float* outrA = out + (size_t)(row0 + 2 * s) * IN_DIM;
        float* outrB = outrA + IN_DIM;

#pragma unroll
        for (int it = 0; it < ITS; ++it) {
            const int j0 = (it * TPB + tid) * 4;
            const uint4 pi = pk[it];

            f32x4 oA, oB;
#define COL(P, CFI, FLD)                                                            \
            {                                                                       \
                float2 a = *(const float2*)(buf + (((P) & 0xFFFFu) << 1));          \
                float2 b = *(const float2*)(buf + (((P) >> 16) << 1));              \
                float c0 = __low2float(cf[it][CFI].ab), c1 = __high2float(cf[it][CFI].ab); \
                float c2 = __low2float(cf[it][CFI].cd), c3 = __high2float(cf[it][CFI].cd); \
                oA.FLD = fmaf(a.x, fmaf(c3, b.x, c1), fmaf(c2, b.x, c0));           \
                oB.FLD = fmaf(a.y, fmaf(c3, b.y, c1), fmaf(c2, b.y, c0));           \
            }
            COL(pi.x, 0, x)
            COL(pi.y, 1, y)
            COL(pi.z, 2, z)
            COL(pi.w, 3, w)
#undef COL
            *(f32x4*)(outrA + j0) = oA;
            *(f32x4*)(outrB + j0) = oB;
        }

        __syncthreads();  // all waves done reading pair s

        if (pf) {
#pragma unroll
            for (int c = 0; c < CHK; ++c) {
                const int m = c * TPB + tid;
                *(f32x4*)((char*)lds + (size_t)m * 16) =
                    f32x4{ta[c].x, tb[c].x, ta[c].y, tb[c].y};
            }
        }
    }
}

extern "C" void kernel_launch(void* const* d_in, const int* in_sizes, int n_in,
                              void* d_out, int out_size, void* d_ws, size_t ws_size,
                              hipStream_t stream) {
    const float* x = (const float*)d_in[0];
    const int* ia = (const int*)d_in[1];
    const int* ib = (const int*)d_in[2];
    const float* w = (const float*)d_in[3];
    float* out = (float*)d_out;

    // ws layout: [0, 128 KiB) coefh h2x2[OUT_DIM]; [128 KiB, 192 KiB) packed u32[OUT_DIM]
    h2x2* coefh = (h2x2*)d_ws;
    unsigned* packed = (unsigned*)((char*)d_ws + (size_t)OUT_DIM * sizeof(h2x2));

    prep_kernel<<<OUT_DIM / 256, 256, 0, stream>>>(w, ia, ib, coefh, packed);
    logic_kernel<<<NBLK, TPB, 0, stream>>>(x, packed, coefh, out);
}